// Round 4
// baseline (231.881 us; speedup 1.0000x reference)
//
#include <hip/hip_runtime.h>

using f16 = _Float16;
typedef _Float16 f16x8 __attribute__((ext_vector_type(8)));
typedef float f32x4 __attribute__((ext_vector_type(4)));

constexpr int Bn    = 32;
constexpr int Sn    = 2048;
constexpr int Fn    = 128;
constexpr int DKn   = 32;
constexpr int NHn   = 16;
constexpr int FILTn = 3;
constexpr int Mn    = Bn * Sn;

// softmax scale (1/sqrt(32)) * log2(e), folded into Wq/bq at prep time.
constexpr float QSCALE = 0.1767766952966369f * 1.4426950408889634f;

// misc layout (float): [0..95] Wo_eff[d*3+f], [96..98] bo,
// [99..130] bq*QSCALE, [131..162] bk, [163..194] bv
constexpr int MISC_WOEFF = 0;
constexpr int MISC_BO    = 96;
constexpr int MISC_BQ    = 99;
constexpr int MISC_BK    = 131;
constexpr int MISC_BV    = 163;

// ---------------------------------------------------------------------------
// Prep kernel: pack W^T into exact MFMA B-fragment order (f16, scaled):
//   wtg[T*4096 + (nt*4+ks)*512 + lane*8 + j]
//     = W_T[(ks*32 + (lane>>4)*8 + j)*32 + nt*16 + (lane&15)] * sc
// Also compute Wo_eff (16 identical heads summed) and scaled biases -> misc.
// ---------------------------------------------------------------------------
__global__ __launch_bounds__(256) void prep_kernel(
    const float* __restrict__ Wq, const float* __restrict__ bq,
    const float* __restrict__ Wk, const float* __restrict__ bk,
    const float* __restrict__ Wv, const float* __restrict__ bv,
    const float* __restrict__ Wo, const float* __restrict__ bo,
    f16* __restrict__ wtg, float* __restrict__ misc)
{
    for (int idx = blockIdx.x * 256 + threadIdx.x; idx < 3 * 4096;
         idx += gridDim.x * 256) {
        const int T    = idx >> 12;
        const int r    = idx & 4095;
        const int nt   = r >> 11;
        const int ks   = (r >> 9) & 3;
        const int lane = (r >> 3) & 63;
        const int j    = r & 7;
        const int k    = ks * 32 + (lane >> 4) * 8 + j;
        const int c    = nt * 16 + (lane & 15);
        const float* W = (T == 0) ? Wq : ((T == 1) ? Wk : Wv);
        const float sc = (T == 0) ? QSCALE : 1.0f;
        wtg[idx] = (f16)(W[k * DKn + c] * sc);
    }
    if (blockIdx.x == 0) {
        const int t = threadIdx.x;
        if (t < 96) {
            const int d = t / 3, f = t - 3 * d;
            float s = 0.f;
#pragma unroll
            for (int h = 0; h < NHn; ++h) s += Wo[(h * DKn + d) * FILTn + f];
            misc[MISC_WOEFF + t] = s;
        } else if (t < 99) {
            misc[MISC_BO + (t - 96)] = bo[t - 96];
        } else if (t < 131) {
            misc[MISC_BQ + (t - 99)] = bq[t - 99] * QSCALE;
        } else if (t < 163) {
            misc[MISC_BK + (t - 131)] = bk[t - 131];
        } else if (t < 195) {
            misc[MISC_BV + (t - 163)] = bv[t - 163];
        }
    }
}

// ---------------------------------------------------------------------------
// Kernel A: QKV projection. One tensor per block (T = blockIdx.x>>10),
// 64 rows per block (wave = 16 rows). W fragments are direct coalesced
// b128 loads from the prepped wtg (L2-hot). 16 independent HBM loads in
// flight per wave. V computed transposed (swap MFMA operands).
// ---------------------------------------------------------------------------
__global__ __launch_bounds__(256, 4) void qkv_proj(
    const float* __restrict__ q_in, const float* __restrict__ k_in,
    const float* __restrict__ v_in,
    const f16* __restrict__ wtg, const float* __restrict__ misc,
    f16* __restrict__ q_ws, f16* __restrict__ k_ws, f16* __restrict__ v_ws)
{
    const int t    = threadIdx.x;
    const int w    = t >> 6;
    const int lane = t & 63;
    const int n    = lane & 15;
    const int quad = lane >> 4;
    const int T    = blockIdx.x >> 10;
    const int row0 = ((blockIdx.x & 1023) * 4 + w) * 16;
    const float* in = (T == 0) ? q_in : ((T == 1) ? k_in : v_in);

    // W fragments: [nt][ks], 8 coalesced 16B loads (same for every wave).
    f16x8 wf[2][4];
#pragma unroll
    for (int nt = 0; nt < 2; ++nt)
#pragma unroll
        for (int ks = 0; ks < 4; ++ks)
            wf[nt][ks] =
                *(const f16x8*)(wtg + T * 4096 + (nt * 4 + ks) * 512 + lane * 8);

    // A fragments: 8 independent float4 HBM loads.
    f16x8 af[4];
#pragma unroll
    for (int ks = 0; ks < 4; ++ks) {
        const float* p  = in + (size_t)(row0 + n) * Fn + ks * 32 + quad * 8;
        const float4 x0 = *(const float4*)p;
        const float4 x1 = *(const float4*)(p + 4);
        f16x8 a;
        a[0]=(f16)x0.x; a[1]=(f16)x0.y; a[2]=(f16)x0.z; a[3]=(f16)x0.w;
        a[4]=(f16)x1.x; a[5]=(f16)x1.y; a[6]=(f16)x1.z; a[7]=(f16)x1.w;
        af[ks] = a;
    }

    if (T < 2) {
        const float* bb = misc + (T == 0 ? MISC_BQ : MISC_BK);
        const float b0 = bb[n], b1 = bb[16 + n];
        f32x4 acc0 = {b0, b0, b0, b0};
        f32x4 acc1 = {b1, b1, b1, b1};
#pragma unroll
        for (int ks = 0; ks < 4; ++ks) {
            acc0 = __builtin_amdgcn_mfma_f32_16x16x32_f16(af[ks], wf[0][ks], acc0, 0, 0, 0);
            acc1 = __builtin_amdgcn_mfma_f32_16x16x32_f16(af[ks], wf[1][ks], acc1, 0, 0, 0);
        }
        f16* ows = (T == 0) ? q_ws : k_ws;
#pragma unroll
        for (int r = 0; r < 4; ++r) {
            const int row = row0 + quad * 4 + r;
            ows[(size_t)row * DKn + n]      = (f16)acc0[r];
            ows[(size_t)row * DKn + 16 + n] = (f16)acc1[r];
        }
    } else {
        f32x4 acc0 = {0.f, 0.f, 0.f, 0.f};
        f32x4 acc1 = {0.f, 0.f, 0.f, 0.f};
#pragma unroll
        for (int ks = 0; ks < 4; ++ks) {
            acc0 = __builtin_amdgcn_mfma_f32_16x16x32_f16(wf[0][ks], af[ks], acc0, 0, 0, 0);
            acc1 = __builtin_amdgcn_mfma_f32_16x16x32_f16(wf[1][ks], af[ks], acc1, 0, 0, 0);
        }
        const int b  = row0 >> 11;            // / Sn
        const int s0 = (row0 & (Sn - 1)) + n;
#pragma unroll
        for (int r = 0; r < 4; ++r) {
            const int d0 = quad * 4 + r;
            v_ws[((size_t)(b * DKn + d0)) * Sn + s0] =
                (f16)(acc0[r] + misc[MISC_BV + d0]);
            v_ws[((size_t)(b * DKn + 16 + d0)) * Sn + s0] =
                (f16)(acc1[r] + misc[MISC_BV + 16 + d0]);
        }
    }
}

// ---------------------------------------------------------------------------
// Kernel B: flash attention (no-max softmax) + fused output projection.
// 4 independent waves / block, zero barriers. K fragments register-prefetched
// one tile ahead (cross-iteration double buffer); V fragments issued at body
// top (consumed ~200 cyc later after QK+softmax+P roundtrip).
// P C-layout -> A-layout via per-wave swizzled f16 LDS (conflict-free, R3).
// ---------------------------------------------------------------------------
__global__ __launch_bounds__(256, 4) void flash_mfma(
    const f16* __restrict__ q_ws, const f16* __restrict__ k_ws,
    const f16* __restrict__ v_ws,
    const float* __restrict__ misc, float* __restrict__ out)
{
    __shared__ f16 psh[4 * 16 * 64];   // 8 KB, per-wave 2 KB, swizzled

    const int t    = threadIdx.x;
    const int w    = t >> 6;
    const int lane = t & 63;
    const int n    = lane & 15;
    const int quad = lane >> 4;
    const int b    = blockIdx.x >> 5;
    const int qt   = blockIdx.x & 31;

    const int qrow0 = b * Sn + qt * 64 + w * 16;
    const f16x8 qa = *(const f16x8*)(q_ws + (size_t)(qrow0 + n) * DKn + quad * 8);

    // P LDS addressing: addr(row,col) = row*64 + ((col>>3 ^ row&7)<<3) + (col&7)
    f16* pw = psh + w * 16 * 64;
    const f16* prd0 = pw + n * 64 + ((quad ^ (n & 7)) << 3);        // ks=0
    const f16* prd1 = pw + n * 64 + (((4 + quad) ^ (n & 7)) << 3);  // ks=1
    int pwo[16];
#pragma unroll
    for (int r = 0; r < 4; ++r) {
        const int row = quad * 4 + r;
#pragma unroll
        for (int g = 0; g < 4; ++g)
            pwo[r * 4 + g] =
                row * 64 + (((g * 2 + (n >> 3)) ^ (row & 7)) << 3) + (n & 7);
    }

    const f16* Kb = k_ws + (size_t)b * Sn * DKn + n * DKn + quad * 8;
    const f16* V0 = v_ws + ((size_t)(b * DKn + n)) * Sn + quad * 8;
    const f16* V1 = v_ws + ((size_t)(b * DKn + 16 + n)) * Sn + quad * 8;

    f32x4 o0 = {0.f, 0.f, 0.f, 0.f};
    f32x4 o1 = {0.f, 0.f, 0.f, 0.f};
    float l[4] = {0.f, 0.f, 0.f, 0.f};
    const f32x4 zero = {0.f, 0.f, 0.f, 0.f};

#define LOADK(K0, K1, K2, K3, KT)                                   \
    {                                                               \
        const f16* kp = Kb + (KT) * 64 * DKn;                       \
        K0 = *(const f16x8*)(kp);                                   \
        K1 = *(const f16x8*)(kp + 16 * DKn);                        \
        K2 = *(const f16x8*)(kp + 32 * DKn);                        \
        K3 = *(const f16x8*)(kp + 48 * DKn);                        \
    }

#define BODY(K0, K1, K2, K3, KT)                                              \
    {                                                                         \
        const f16x8 va0 = *(const f16x8*)(V0 + (KT) * 64);                    \
        const f16x8 va1 = *(const f16x8*)(V0 + (KT) * 64 + 32);               \
        const f16x8 va2 = *(const f16x8*)(V1 + (KT) * 64);                    \
        const f16x8 va3 = *(const f16x8*)(V1 + (KT) * 64 + 32);               \
        const f32x4 s0 = __builtin_amdgcn_mfma_f32_16x16x32_f16(qa, K0, zero, 0, 0, 0); \
        const f32x4 s1 = __builtin_amdgcn_mfma_f32_16x16x32_f16(qa, K1, zero, 0, 0, 0); \
        const f32x4 s2 = __builtin_amdgcn_mfma_f32_16x16x32_f16(qa, K2, zero, 0, 0, 0); \
        const f32x4 s3 = __builtin_amdgcn_mfma_f32_16x16x32_f16(qa, K3, zero, 0, 0, 0); \
        _Pragma("unroll")                                                     \
        for (int r = 0; r < 4; ++r) {                                         \
            const float p0 = __builtin_amdgcn_exp2f(s0[r]);                   \
            const float p1 = __builtin_amdgcn_exp2f(s1[r]);                   \
            const float p2 = __builtin_amdgcn_exp2f(s2[r]);                   \
            const float p3 = __builtin_amdgcn_exp2f(s3[r]);                   \
            l[r] += (p0 + p1) + (p2 + p3);                                    \
            pw[pwo[r * 4 + 0]] = (f16)p0;                                     \
            pw[pwo[r * 4 + 1]] = (f16)p1;                                     \
            pw[pwo[r * 4 + 2]] = (f16)p2;                                     \
            pw[pwo[r * 4 + 3]] = (f16)p3;                                     \
        }                                                                     \
        const f16x8 pa0 = *(const f16x8*)prd0;                                \
        const f16x8 pa1 = *(const f16x8*)prd1;                                \
        o0 = __builtin_amdgcn_mfma_f32_16x16x32_f16(pa0, va0, o0, 0, 0, 0);   \
        o0 = __builtin_amdgcn_mfma_f32_16x16x32_f16(pa1, va1, o0, 0, 0, 0);   \
        o1 = __builtin_amdgcn_mfma_f32_16x16x32_f16(pa0, va2, o1, 0, 0, 0);   \
        o1 = __builtin_amdgcn_mfma_f32_16x16x32_f16(pa1, va3, o1, 0, 0, 0);   \
    }

    f16x8 ck0, ck1, ck2, ck3, nk0, nk1, nk2, nk3;
    LOADK(ck0, ck1, ck2, ck3, 0)
#pragma unroll 1
    for (int kt = 0; kt < Sn / 64; kt += 2) {
        LOADK(nk0, nk1, nk2, nk3, kt + 1)
        BODY(ck0, ck1, ck2, ck3, kt)
        LOADK(ck0, ck1, ck2, ck3, (kt + 2) & 31)
        BODY(nk0, nk1, nk2, nk3, kt + 1)
    }
#undef LOADK
#undef BODY

    // l reduction across the 16-lane group
#pragma unroll
    for (int r = 0; r < 4; ++r) {
        float v = l[r];
        v += __shfl_xor(v, 1, 16);
        v += __shfl_xor(v, 2, 16);
        v += __shfl_xor(v, 4, 16);
        v += __shfl_xor(v, 8, 16);
        l[r] = v;
    }

    // epilogue: out[row][f] = sum_d (O[row][d]/l) * Wo_eff[d][f] + bo[f]
    float w0f[FILTn], w1f[FILTn];
#pragma unroll
    for (int f = 0; f < FILTn; ++f) {
        w0f[f] = misc[MISC_WOEFF + n * FILTn + f];
        w1f[f] = misc[MISC_WOEFF + (16 + n) * FILTn + f];
    }
#pragma unroll
    for (int r = 0; r < 4; ++r) {
        const float inv = 1.f / l[r];
        const float a0 = o0[r] * inv;
        const float a1 = o1[r] * inv;
#pragma unroll
        for (int f = 0; f < FILTn; ++f) {
            float v = a0 * w0f[f] + a1 * w1f[f];
            v += __shfl_xor(v, 1, 16);
            v += __shfl_xor(v, 2, 16);
            v += __shfl_xor(v, 4, 16);
            v += __shfl_xor(v, 8, 16);
            if (n == f) {
                const int row = qrow0 + quad * 4 + r;
                out[(size_t)row * FILTn + f] = v + misc[MISC_BO + f];
            }
        }
    }
}

// ---------------------------------------------------------------------------
// Launch. ws layout (f16 elems): q_ws | k_ws | v_ws (4 MiB each), then
// wtg (12288 f16), then misc (195 f32, 4B-aligned).
// ---------------------------------------------------------------------------
extern "C" void kernel_launch(void* const* d_in, const int* in_sizes, int n_in,
                              void* d_out, int out_size, void* d_ws,
                              size_t ws_size, hipStream_t stream)
{
    const float* q_in = (const float*)d_in[0];
    const float* k_in = (const float*)d_in[1];
    const float* v_in = (const float*)d_in[2];
    const float* Wq   = (const float*)d_in[3];
    const float* bq   = (const float*)d_in[4];
    const float* Wk   = (const float*)d_in[5];
    const float* bk   = (const float*)d_in[6];
    const float* Wv   = (const float*)d_in[7];
    const float* bv   = (const float*)d_in[8];
    const float* Wo   = (const float*)d_in[9];
    const float* bo   = (const float*)d_in[10];
    float* out = (float*)d_out;

    f16*   ws   = (f16*)d_ws;
    f16*   q_ws = ws;
    f16*   k_ws = ws + (size_t)Mn * DKn;
    f16*   v_ws = ws + 2 * (size_t)Mn * DKn;
    f16*   wtg  = ws + 3 * (size_t)Mn * DKn;
    float* misc = (float*)(wtg + 3 * 4096);

    prep_kernel<<<16, 256, 0, stream>>>(Wq, bq, Wk, bk, Wv, bv, Wo, bo, wtg, misc);

    qkv_proj<<<3 * 1024, 256, 0, stream>>>(
        q_in, k_in, v_in, wtg, misc, q_ws, k_ws, v_ws);

    flash_mfma<<<Bn * (Sn / 64), 256, 0, stream>>>(
        q_ws, k_ws, v_ws, misc, out);
}

// Round 5
// 195.165 us; speedup vs baseline: 1.1881x; 1.1881x over previous
//
#include <hip/hip_runtime.h>
#include <stdint.h>

using f16 = _Float16;
typedef _Float16 f16x8 __attribute__((ext_vector_type(8)));
typedef float f32x4 __attribute__((ext_vector_type(4)));

constexpr int Bn    = 32;
constexpr int Sn    = 2048;
constexpr int Fn    = 128;
constexpr int DKn   = 32;
constexpr int NHn   = 16;
constexpr int FILTn = 3;
constexpr int Mn    = Bn * Sn;

// softmax scale (1/sqrt(32)) * log2(e), folded into Wq/bq at prep time.
constexpr float QSCALE = 0.1767766952966369f * 1.4426950408889634f;

// misc layout (float)
constexpr int MISC_WOEFF = 0;
constexpr int MISC_BO    = 96;
constexpr int MISC_BQ    = 99;
constexpr int MISC_BK    = 131;
constexpr int MISC_BV    = 163;

// Async global->LDS 16B copy. LDS dest = wave-uniform base + lane*16 (m104).
#define ASYNC_COPY16(gp, lp)                                                   \
    __builtin_amdgcn_global_load_lds(                                          \
        (const __attribute__((address_space(1))) uint32_t*)(const void*)(gp),  \
        (__attribute__((address_space(3))) uint32_t*)(lp), 16, 0, 0)

// s_waitcnt imm: [3:0] vmcnt, [6:4] expcnt, [11:8] lgkmcnt
#define WAIT_VM2 __builtin_amdgcn_s_waitcnt(0xF72)  // vmcnt<=2, lgkm/exp free
#define WAIT_VM0 __builtin_amdgcn_s_waitcnt(0xF70)  // vmcnt<=0

// ---------------------------------------------------------------------------
// Prep kernel: pack W^T into MFMA B-fragment order (f16, scaled) + misc.
// ---------------------------------------------------------------------------
__global__ __launch_bounds__(256) void prep_kernel(
    const float* __restrict__ Wq, const float* __restrict__ bq,
    const float* __restrict__ Wk, const float* __restrict__ bk,
    const float* __restrict__ Wv, const float* __restrict__ bv,
    const float* __restrict__ Wo, const float* __restrict__ bo,
    f16* __restrict__ wtg, float* __restrict__ misc)
{
    for (int idx = blockIdx.x * 256 + threadIdx.x; idx < 3 * 4096;
         idx += gridDim.x * 256) {
        const int T    = idx >> 12;
        const int r    = idx & 4095;
        const int nt   = r >> 11;
        const int ks   = (r >> 9) & 3;
        const int lane = (r >> 3) & 63;
        const int j    = r & 7;
        const int k    = ks * 32 + (lane >> 4) * 8 + j;
        const int c    = nt * 16 + (lane & 15);
        const float* W = (T == 0) ? Wq : ((T == 1) ? Wk : Wv);
        const float sc = (T == 0) ? QSCALE : 1.0f;
        wtg[idx] = (f16)(W[k * DKn + c] * sc);
    }
    if (blockIdx.x == 0) {
        const int t = threadIdx.x;
        if (t < 96) {
            const int d = t / 3, f = t - 3 * d;
            float s = 0.f;
#pragma unroll
            for (int h = 0; h < NHn; ++h) s += Wo[(h * DKn + d) * FILTn + f];
            misc[MISC_WOEFF + t] = s;
        } else if (t < 99) {
            misc[MISC_BO + (t - 96)] = bo[t - 96];
        } else if (t < 131) {
            misc[MISC_BQ + (t - 99)] = bq[t - 99] * QSCALE;
        } else if (t < 163) {
            misc[MISC_BK + (t - 131)] = bk[t - 131];
        } else if (t < 195) {
            misc[MISC_BV + (t - 163)] = bv[t - 163];
        }
    }
}

// ---------------------------------------------------------------------------
// Kernel A: QKV projection (one tensor per block, T = blockIdx.x>>10).
// K output goes to a DMA-image tile layout:
//   k_ws f16 index = (b*32+kt)*2048 + ((key>>1)*8 + (key&1)*4 + (d>>3))*8 + (d&7)
// (128-B rows holding key pairs), so flash's global_load_lds deposits it
// ready for conflict-clean ds_read_b128 fragments.
// V output transposed [b][d][s] (128-B rows per d per tile) — DMA-compatible.
// ---------------------------------------------------------------------------
__global__ __launch_bounds__(256, 4) void qkv_proj(
    const float* __restrict__ q_in, const float* __restrict__ k_in,
    const float* __restrict__ v_in,
    const f16* __restrict__ wtg, const float* __restrict__ misc,
    f16* __restrict__ q_ws, f16* __restrict__ k_ws, f16* __restrict__ v_ws)
{
    const int t    = threadIdx.x;
    const int w    = t >> 6;
    const int lane = t & 63;
    const int n    = lane & 15;
    const int quad = lane >> 4;
    const int T    = blockIdx.x >> 10;
    const int row0 = ((blockIdx.x & 1023) * 4 + w) * 16;
    const float* in = (T == 0) ? q_in : ((T == 1) ? k_in : v_in);

    // W fragments (L2-hot, coalesced).
    f16x8 wf[2][4];
#pragma unroll
    for (int nt = 0; nt < 2; ++nt)
#pragma unroll
        for (int ks = 0; ks < 4; ++ks)
            wf[nt][ks] =
                *(const f16x8*)(wtg + T * 4096 + (nt * 4 + ks) * 512 + lane * 8);

    // A fragments: 8 independent float4 HBM loads.
    f16x8 af[4];
#pragma unroll
    for (int ks = 0; ks < 4; ++ks) {
        const float* p  = in + (size_t)(row0 + n) * Fn + ks * 32 + quad * 8;
        const float4 x0 = *(const float4*)p;
        const float4 x1 = *(const float4*)(p + 4);
        f16x8 a;
        a[0]=(f16)x0.x; a[1]=(f16)x0.y; a[2]=(f16)x0.z; a[3]=(f16)x0.w;
        a[4]=(f16)x1.x; a[5]=(f16)x1.y; a[6]=(f16)x1.z; a[7]=(f16)x1.w;
        af[ks] = a;
    }

    if (T < 2) {
        const float* bb = misc + (T == 0 ? MISC_BQ : MISC_BK);
        const float b0 = bb[n], b1 = bb[16 + n];
        f32x4 acc0 = {b0, b0, b0, b0};
        f32x4 acc1 = {b1, b1, b1, b1};
#pragma unroll
        for (int ks = 0; ks < 4; ++ks) {
            acc0 = __builtin_amdgcn_mfma_f32_16x16x32_f16(af[ks], wf[0][ks], acc0, 0, 0, 0);
            acc1 = __builtin_amdgcn_mfma_f32_16x16x32_f16(af[ks], wf[1][ks], acc1, 0, 0, 0);
        }
        if (T == 0) {
#pragma unroll
            for (int r = 0; r < 4; ++r) {
                const int row = row0 + quad * 4 + r;
                q_ws[(size_t)row * DKn + n]      = (f16)acc0[r];
                q_ws[(size_t)row * DKn + 16 + n] = (f16)acc1[r];
            }
        } else {
#pragma unroll
            for (int r = 0; r < 4; ++r) {
                const int row = row0 + quad * 4 + r;
                const int b   = row >> 11;
                const int s   = row & (Sn - 1);
                const int kt  = s >> 6;
                const int key = s & 63;
                const size_t tbase = ((size_t)b * 32 + kt) * 2048;
                const int b16 = ((key >> 1) << 3) | ((key & 1) << 2);
                k_ws[tbase + (size_t)(b16 + (n >> 3)) * 8 + (n & 7)]     = (f16)acc0[r];
                k_ws[tbase + (size_t)(b16 + 2 + (n >> 3)) * 8 + (n & 7)] = (f16)acc1[r];
            }
        }
    } else {
        f32x4 acc0 = {0.f, 0.f, 0.f, 0.f};
        f32x4 acc1 = {0.f, 0.f, 0.f, 0.f};
#pragma unroll
        for (int ks = 0; ks < 4; ++ks) {
            acc0 = __builtin_amdgcn_mfma_f32_16x16x32_f16(wf[0][ks], af[ks], acc0, 0, 0, 0);
            acc1 = __builtin_amdgcn_mfma_f32_16x16x32_f16(wf[1][ks], af[ks], acc1, 0, 0, 0);
        }
        const int b  = row0 >> 11;
        const int s0 = (row0 & (Sn - 1)) + n;
#pragma unroll
        for (int r = 0; r < 4; ++r) {
            const int d0 = quad * 4 + r;
            v_ws[((size_t)(b * DKn + d0)) * Sn + s0] =
                (f16)(acc0[r] + misc[MISC_BV + d0]);
            v_ws[((size_t)(b * DKn + 16 + d0)) * Sn + s0] =
                (f16)(acc1[r] + misc[MISC_BV + 16 + d0]);
        }
    }
}

// ---------------------------------------------------------------------------
// Kernel B: flash attention (no-max softmax) + fused output projection.
// K/V tiles staged block-wide via global_load_lds, triple-buffered, prefetch
// distance 2, manual vmcnt + raw s_barrier (prefetch survives the barrier).
// XCD swizzle: batch = (blockIdx&7)*4 + (blockIdx>>8) -> 4 batches per XCD,
// K+V+Q working set ~1.5 MB fits the 4 MB per-XCD L2.
// ---------------------------------------------------------------------------
__global__ __launch_bounds__(256, 4) void flash_mfma(
    const f16* __restrict__ q_ws, const f16* __restrict__ k_ws,
    const f16* __restrict__ v_ws,
    const float* __restrict__ misc, float* __restrict__ out)
{
    __shared__ f16 kv[3][2][2048];     // [buf][K/V][4 KB tile] = 24 KB
    __shared__ f16 psh[4 * 16 * 64];   // 8 KB, per-wave 2 KB, swizzled

    const int t    = threadIdx.x;
    const int w    = t >> 6;
    const int lane = t & 63;
    const int n    = lane & 15;
    const int quad = lane >> 4;
    const int b    = (blockIdx.x & 7) * 4 + (blockIdx.x >> 8);
    const int qt   = (blockIdx.x >> 3) & 31;

    const f16* Ktiles = k_ws + (size_t)b * Sn * DKn;   // 32 tiles x 2048 f16
    const f16* Vbase  = v_ws + (size_t)b * DKn * Sn;

#define STAGE(KT, BUF)                                                          \
    {                                                                           \
        ASYNC_COPY16(Ktiles + (size_t)(KT) * 2048 + t * 8, &kv[BUF][0][w * 512]); \
        ASYNC_COPY16(Vbase + (size_t)(t >> 3) * Sn + (KT) * 64 + (t & 7) * 8,   \
                     &kv[BUF][1][w * 512]);                                     \
    }

    const int qrow0 = b * Sn + qt * 64 + w * 16;
    const f16x8 qa = *(const f16x8*)(q_ws + (size_t)(qrow0 + n) * DKn + quad * 8);

    // Fragment LDS offsets (f16 units), fixed per lane.
    int koff[4];   // K frag, key group g: chunk = ((g*16+n)>>1)*8 + (n&1)*4 + quad
#pragma unroll
    for (int g = 0; g < 4; ++g)
        koff[g] = ((((g * 16 + n) >> 1) * 8 + (n & 1) * 4 + quad)) * 8;
    int voff[2][2];  // V frag [d-half][ks]: chunk = d*8 + ks*4 + quad
#pragma unroll
    for (int ks = 0; ks < 2; ++ks) {
        voff[0][ks] = (n * 8 + ks * 4 + quad) * 8;
        voff[1][ks] = ((16 + n) * 8 + ks * 4 + quad) * 8;
    }

    // P LDS addressing (R3-verified conflict-free).
    f16* pw = psh + w * 16 * 64;
    const f16* prd0 = pw + n * 64 + ((quad ^ (n & 7)) << 3);
    const f16* prd1 = pw + n * 64 + (((4 + quad) ^ (n & 7)) << 3);
    int pwo[16];
#pragma unroll
    for (int r = 0; r < 4; ++r) {
        const int row = quad * 4 + r;
#pragma unroll
        for (int g = 0; g < 4; ++g)
            pwo[r * 4 + g] =
                row * 64 + (((g * 2 + (n >> 3)) ^ (row & 7)) << 3) + (n & 7);
    }

    f32x4 o0 = {0.f, 0.f, 0.f, 0.f};
    f32x4 o1 = {0.f, 0.f, 0.f, 0.f};
    float l[4] = {0.f, 0.f, 0.f, 0.f};
    const f32x4 zero = {0.f, 0.f, 0.f, 0.f};

    STAGE(0, 0)
    STAGE(1, 1)

#pragma unroll 1
    for (int kt = 0; kt < Sn / 64; ++kt) {
        const int cur = kt % 3;
        WAIT_VM2;                          // tile kt's 2 DMA instrs complete
        __builtin_amdgcn_s_barrier();      // all 4 waves' quarters visible
        STAGE((kt + 2) & 31, (kt + 2) % 3) // prefetch distance 2

        const f16* Kt = &kv[cur][0][0];
        const f16* Vt = &kv[cur][1][0];

        const f16x8 kb0 = *(const f16x8*)(Kt + koff[0]);
        const f16x8 kb1 = *(const f16x8*)(Kt + koff[1]);
        const f16x8 kb2 = *(const f16x8*)(Kt + koff[2]);
        const f16x8 kb3 = *(const f16x8*)(Kt + koff[3]);
        const f16x8 va0 = *(const f16x8*)(Vt + voff[0][0]);
        const f16x8 va1 = *(const f16x8*)(Vt + voff[0][1]);
        const f16x8 va2 = *(const f16x8*)(Vt + voff[1][0]);
        const f16x8 va3 = *(const f16x8*)(Vt + voff[1][1]);

        const f32x4 s0 = __builtin_amdgcn_mfma_f32_16x16x32_f16(qa, kb0, zero, 0, 0, 0);
        const f32x4 s1 = __builtin_amdgcn_mfma_f32_16x16x32_f16(qa, kb1, zero, 0, 0, 0);
        const f32x4 s2 = __builtin_amdgcn_mfma_f32_16x16x32_f16(qa, kb2, zero, 0, 0, 0);
        const f32x4 s3 = __builtin_amdgcn_mfma_f32_16x16x32_f16(qa, kb3, zero, 0, 0, 0);

#pragma unroll
        for (int r = 0; r < 4; ++r) {
            const float p0 = __builtin_amdgcn_exp2f(s0[r]);
            const float p1 = __builtin_amdgcn_exp2f(s1[r]);
            const float p2 = __builtin_amdgcn_exp2f(s2[r]);
            const float p3 = __builtin_amdgcn_exp2f(s3[r]);
            l[r] += (p0 + p1) + (p2 + p3);
            pw[pwo[r * 4 + 0]] = (f16)p0;
            pw[pwo[r * 4 + 1]] = (f16)p1;
            pw[pwo[r * 4 + 2]] = (f16)p2;
            pw[pwo[r * 4 + 3]] = (f16)p3;
        }

        const f16x8 pa0 = *(const f16x8*)prd0;
        const f16x8 pa1 = *(const f16x8*)prd1;
        o0 = __builtin_amdgcn_mfma_f32_16x16x32_f16(pa0, va0, o0, 0, 0, 0);
        o0 = __builtin_amdgcn_mfma_f32_16x16x32_f16(pa1, va1, o0, 0, 0, 0);
        o1 = __builtin_amdgcn_mfma_f32_16x16x32_f16(pa0, va2, o1, 0, 0, 0);
        o1 = __builtin_amdgcn_mfma_f32_16x16x32_f16(pa1, va3, o1, 0, 0, 0);
    }
#undef STAGE
    WAIT_VM0;   // drain redundant tail DMAs before LDS is reallocated

    // l reduction across the 16-lane group
#pragma unroll
    for (int r = 0; r < 4; ++r) {
        float v = l[r];
        v += __shfl_xor(v, 1, 16);
        v += __shfl_xor(v, 2, 16);
        v += __shfl_xor(v, 4, 16);
        v += __shfl_xor(v, 8, 16);
        l[r] = v;
    }

    // epilogue: out[row][f] = sum_d (O[row][d]/l) * Wo_eff[d][f] + bo[f]
    float w0f[FILTn], w1f[FILTn];
#pragma unroll
    for (int f = 0; f < FILTn; ++f) {
        w0f[f] = misc[MISC_WOEFF + n * FILTn + f];
        w1f[f] = misc[MISC_WOEFF + (16 + n) * FILTn + f];
    }
#pragma unroll
    for (int r = 0; r < 4; ++r) {
        const float inv = 1.f / l[r];
        const float a0 = o0[r] * inv;
        const float a1 = o1[r] * inv;
#pragma unroll
        for (int f = 0; f < FILTn; ++f) {
            float v = a0 * w0f[f] + a1 * w1f[f];
            v += __shfl_xor(v, 1, 16);
            v += __shfl_xor(v, 2, 16);
            v += __shfl_xor(v, 4, 16);
            v += __shfl_xor(v, 8, 16);
            if (n == f) {
                const int row = qrow0 + quad * 4 + r;
                out[(size_t)row * FILTn + f] = v + misc[MISC_BO + f];
            }
        }
    }
}

// ---------------------------------------------------------------------------
// Launch. ws layout (f16): q_ws | k_ws | v_ws (4 MiB each), wtg, misc.
// ---------------------------------------------------------------------------
extern "C" void kernel_launch(void* const* d_in, const int* in_sizes, int n_in,
                              void* d_out, int out_size, void* d_ws,
                              size_t ws_size, hipStream_t stream)
{
    const float* q_in = (const float*)d_in[0];
    const float* k_in = (const float*)d_in[1];
    const float* v_in = (const float*)d_in[2];
    const float* Wq   = (const float*)d_in[3];
    const float* bq   = (const float*)d_in[4];
    const float* Wk   = (const float*)d_in[5];
    const float* bk   = (const float*)d_in[6];
    const float* Wv   = (const float*)d_in[7];
    const float* bv   = (const float*)d_in[8];
    const float* Wo   = (const float*)d_in[9];
    const float* bo   = (const float*)d_in[10];
    float* out = (float*)d_out;

    f16*   ws   = (f16*)d_ws;
    f16*   q_ws = ws;
    f16*   k_ws = ws + (size_t)Mn * DKn;
    f16*   v_ws = ws + 2 * (size_t)Mn * DKn;
    f16*   wtg  = ws + 3 * (size_t)Mn * DKn;
    float* misc = (float*)(wtg + 3 * 4096);

    prep_kernel<<<16, 256, 0, stream>>>(Wq, bq, Wk, bk, Wv, bv, Wo, bo, wtg, misc);

    qkv_proj<<<3 * 1024, 256, 0, stream>>>(
        q_in, k_in, v_in, wtg, misc, q_ws, k_ws, v_ws);

    flash_mfma<<<Bn * (Sn / 64), 256, 0, stream>>>(
        q_ws, k_ws, v_ws, misc, out);
}

// Round 6
// 185.785 us; speedup vs baseline: 1.2481x; 1.0505x over previous
//
#include <hip/hip_runtime.h>
#include <stdint.h>

using f16 = _Float16;
typedef _Float16 f16x8 __attribute__((ext_vector_type(8)));
typedef float f32x4 __attribute__((ext_vector_type(4)));

constexpr int Bn    = 32;
constexpr int Sn    = 2048;
constexpr int Fn    = 128;
constexpr int DKn   = 32;
constexpr int NHn   = 16;
constexpr int FILTn = 3;
constexpr int Mn    = Bn * Sn;

// softmax scale (1/sqrt(32)) * log2(e), folded into Wq/bq at prep time.
constexpr float QSCALE = 0.1767766952966369f * 1.4426950408889634f;

// misc layout (float)
constexpr int MISC_WOEFF = 0;
constexpr int MISC_BO    = 96;
constexpr int MISC_BQ    = 99;
constexpr int MISC_BK    = 131;
constexpr int MISC_BV    = 163;

// Async global->LDS 16B copy. LDS dest = wave-uniform base + lane*16 (m104).
#define ASYNC_COPY16(gp, lp)                                                   \
    __builtin_amdgcn_global_load_lds(                                          \
        (const __attribute__((address_space(1))) uint32_t*)(const void*)(gp),  \
        (__attribute__((address_space(3))) uint32_t*)(lp), 16, 0, 0)

// s_waitcnt imm: [3:0] vmcnt, [6:4] expcnt, [11:8] lgkmcnt
#define WAIT_VM2 __builtin_amdgcn_s_waitcnt(0xF72)  // vmcnt<=2
#define WAIT_VM0 __builtin_amdgcn_s_waitcnt(0xF70)  // vmcnt<=0

// ---------------------------------------------------------------------------
// Prep kernel: pack W^T into MFMA B-fragment order (f16, scaled) + misc.
// ---------------------------------------------------------------------------
__global__ __launch_bounds__(256) void prep_kernel(
    const float* __restrict__ Wq, const float* __restrict__ bq,
    const float* __restrict__ Wk, const float* __restrict__ bk,
    const float* __restrict__ Wv, const float* __restrict__ bv,
    const float* __restrict__ Wo, const float* __restrict__ bo,
    f16* __restrict__ wtg, float* __restrict__ misc)
{
    for (int idx = blockIdx.x * 256 + threadIdx.x; idx < 3 * 4096;
         idx += gridDim.x * 256) {
        const int T    = idx >> 12;
        const int r    = idx & 4095;
        const int nt   = r >> 11;
        const int ks   = (r >> 9) & 3;
        const int lane = (r >> 3) & 63;
        const int j    = r & 7;
        const int k    = ks * 32 + (lane >> 4) * 8 + j;
        const int c    = nt * 16 + (lane & 15);
        const float* W = (T == 0) ? Wq : ((T == 1) ? Wk : Wv);
        const float sc = (T == 0) ? QSCALE : 1.0f;
        wtg[idx] = (f16)(W[k * DKn + c] * sc);
    }
    if (blockIdx.x == 0) {
        const int t = threadIdx.x;
        if (t < 96) {
            const int d = t / 3, f = t - 3 * d;
            float s = 0.f;
#pragma unroll
            for (int h = 0; h < NHn; ++h) s += Wo[(h * DKn + d) * FILTn + f];
            misc[MISC_WOEFF + t] = s;
        } else if (t < 99) {
            misc[MISC_BO + (t - 96)] = bo[t - 96];
        } else if (t < 131) {
            misc[MISC_BQ + (t - 99)] = bq[t - 99] * QSCALE;
        } else if (t < 163) {
            misc[MISC_BK + (t - 131)] = bk[t - 131];
        } else if (t < 195) {
            misc[MISC_BV + (t - 163)] = bv[t - 163];
        }
    }
}

// ---------------------------------------------------------------------------
// Kernel A: QKV projection. One tensor per block-range (T = blockIdx.x/512),
// 128 rows per block: each wave handles TWO 16-row groups (32 rows) so 16
// independent HBM float4 loads are in flight per wave (MLP ~2x R5).
// Outputs: q_ws [row][d] (pre-scaled), k_ws [row][d], v_ws [b][d][s].
// ---------------------------------------------------------------------------
__global__ __launch_bounds__(256) void qkv_proj(
    const float* __restrict__ q_in, const float* __restrict__ k_in,
    const float* __restrict__ v_in,
    const f16* __restrict__ wtg, const float* __restrict__ misc,
    f16* __restrict__ q_ws, f16* __restrict__ k_ws, f16* __restrict__ v_ws)
{
    const int t    = threadIdx.x;
    const int w    = t >> 6;
    const int lane = t & 63;
    const int n    = lane & 15;
    const int quad = lane >> 4;
    const int T    = blockIdx.x / 512;
    const int rowA = (((blockIdx.x - T * 512) * 4 + w)) * 32;   // group A
    const int rowB = rowA + 16;                                  // group B
    const float* in = (T == 0) ? q_in : ((T == 1) ? k_in : v_in);

    // W fragments (L2-hot, coalesced; shared by both groups).
    f16x8 wf[2][4];
#pragma unroll
    for (int nt = 0; nt < 2; ++nt)
#pragma unroll
        for (int ks = 0; ks < 4; ++ks)
            wf[nt][ks] =
                *(const f16x8*)(wtg + T * 4096 + (nt * 4 + ks) * 512 + lane * 8);

    // A fragments: 16 independent float4 HBM loads (8 per group).
    f16x8 afA[4], afB[4];
#pragma unroll
    for (int ks = 0; ks < 4; ++ks) {
        const float* pA = in + (size_t)(rowA + n) * Fn + ks * 32 + quad * 8;
        const float* pB = in + (size_t)(rowB + n) * Fn + ks * 32 + quad * 8;
        const float4 a0 = *(const float4*)pA;
        const float4 a1 = *(const float4*)(pA + 4);
        const float4 b0 = *(const float4*)pB;
        const float4 b1 = *(const float4*)(pB + 4);
        f16x8 a, b;
        a[0]=(f16)a0.x; a[1]=(f16)a0.y; a[2]=(f16)a0.z; a[3]=(f16)a0.w;
        a[4]=(f16)a1.x; a[5]=(f16)a1.y; a[6]=(f16)a1.z; a[7]=(f16)a1.w;
        b[0]=(f16)b0.x; b[1]=(f16)b0.y; b[2]=(f16)b0.z; b[3]=(f16)b0.w;
        b[4]=(f16)b1.x; b[5]=(f16)b1.y; b[6]=(f16)b1.z; b[7]=(f16)b1.w;
        afA[ks] = a;
        afB[ks] = b;
    }

    if (T < 2) {
        const float* bb = misc + (T == 0 ? MISC_BQ : MISC_BK);
        const float b0 = bb[n], b1 = bb[16 + n];
        f32x4 accA0 = {b0, b0, b0, b0}, accA1 = {b1, b1, b1, b1};
        f32x4 accB0 = {b0, b0, b0, b0}, accB1 = {b1, b1, b1, b1};
#pragma unroll
        for (int ks = 0; ks < 4; ++ks) {
            accA0 = __builtin_amdgcn_mfma_f32_16x16x32_f16(afA[ks], wf[0][ks], accA0, 0, 0, 0);
            accA1 = __builtin_amdgcn_mfma_f32_16x16x32_f16(afA[ks], wf[1][ks], accA1, 0, 0, 0);
            accB0 = __builtin_amdgcn_mfma_f32_16x16x32_f16(afB[ks], wf[0][ks], accB0, 0, 0, 0);
            accB1 = __builtin_amdgcn_mfma_f32_16x16x32_f16(afB[ks], wf[1][ks], accB1, 0, 0, 0);
        }
        f16* ows = (T == 0) ? q_ws : k_ws;
#pragma unroll
        for (int r = 0; r < 4; ++r) {
            const int ra = rowA + quad * 4 + r;
            const int rb = rowB + quad * 4 + r;
            ows[(size_t)ra * DKn + n]      = (f16)accA0[r];
            ows[(size_t)ra * DKn + 16 + n] = (f16)accA1[r];
            ows[(size_t)rb * DKn + n]      = (f16)accB0[r];
            ows[(size_t)rb * DKn + 16 + n] = (f16)accB1[r];
        }
    } else {
        f32x4 accA0 = {0.f,0.f,0.f,0.f}, accA1 = {0.f,0.f,0.f,0.f};
        f32x4 accB0 = {0.f,0.f,0.f,0.f}, accB1 = {0.f,0.f,0.f,0.f};
#pragma unroll
        for (int ks = 0; ks < 4; ++ks) {
            accA0 = __builtin_amdgcn_mfma_f32_16x16x32_f16(wf[0][ks], afA[ks], accA0, 0, 0, 0);
            accA1 = __builtin_amdgcn_mfma_f32_16x16x32_f16(wf[1][ks], afA[ks], accA1, 0, 0, 0);
            accB0 = __builtin_amdgcn_mfma_f32_16x16x32_f16(wf[0][ks], afB[ks], accB0, 0, 0, 0);
            accB1 = __builtin_amdgcn_mfma_f32_16x16x32_f16(wf[1][ks], afB[ks], accB1, 0, 0, 0);
        }
        const int b  = rowA >> 11;
        const int sA = (rowA & (Sn - 1)) + n;
        const int sB = sA + 16;
#pragma unroll
        for (int r = 0; r < 4; ++r) {
            const int d0 = quad * 4 + r;
            v_ws[((size_t)(b * DKn + d0)) * Sn + sA] =
                (f16)(accA0[r] + misc[MISC_BV + d0]);
            v_ws[((size_t)(b * DKn + 16 + d0)) * Sn + sA] =
                (f16)(accA1[r] + misc[MISC_BV + 16 + d0]);
            v_ws[((size_t)(b * DKn + d0)) * Sn + sB] =
                (f16)(accB0[r] + misc[MISC_BV + d0]);
            v_ws[((size_t)(b * DKn + 16 + d0)) * Sn + sB] =
                (f16)(accB1[r] + misc[MISC_BV + 16 + d0]);
        }
    }
}

// ---------------------------------------------------------------------------
// Kernel B: flash attention + fused output projection.
// K/V tiles staged via global_load_lds (triple buffer, prefetch distance 2,
// manual vmcnt + raw s_barrier). Bank-conflict-free by construction: the
// swizzle is baked into the per-lane DMA *source* addresses (LDS image chunk
// c holds K(key=c>>2, q=(c&3)^((c>>3)&3)) and V(d=c>>3, j=(c&7)^((c>>3)&7))),
// so every ds_read_b128 octet hits 8 distinct bank-quads (same criterion as
// the P pattern, measured 0 conflicts R3-R5).
// XCD swizzle: batch = (blockIdx&7)*4 + (blockIdx>>8) -> ~1.5 MB/XCD-L2.
// ---------------------------------------------------------------------------
__global__ __launch_bounds__(256, 4) void flash_mfma(
    const f16* __restrict__ q_ws, const f16* __restrict__ k_ws,
    const f16* __restrict__ v_ws,
    const float* __restrict__ misc, float* __restrict__ out)
{
    __shared__ f16 kv[3][2][2048];     // [buf][K/V][4 KB tile] = 24 KB
    __shared__ f16 psh[4 * 16 * 64];   // 8 KB, per-wave 2 KB, swizzled

    const int t    = threadIdx.x;
    const int w    = t >> 6;
    const int lane = t & 63;
    const int n    = lane & 15;
    const int quad = lane >> 4;
    const int b    = (blockIdx.x & 7) * 4 + (blockIdx.x >> 8);
    const int qt   = (blockIdx.x >> 3) & 31;

    // Swizzled per-lane DMA source offsets (f16 units, tile-relative).
    const f16* Ksrc = k_ws + (size_t)b * Sn * DKn
                    + (size_t)(t >> 2) * DKn + (((t & 3) ^ ((t >> 3) & 3)) * 8);
    const f16* Vsrc = v_ws + (size_t)b * DKn * Sn
                    + (size_t)(t >> 3) * Sn + (((t & 7) ^ ((t >> 3) & 7)) * 8);

#define STAGE(KT, BUF)                                              \
    {                                                               \
        ASYNC_COPY16(Ksrc + (size_t)(KT) * 2048, &kv[BUF][0][w * 512]); \
        ASYNC_COPY16(Vsrc + (size_t)(KT) * 64,   &kv[BUF][1][w * 512]); \
    }

    const int qrow0 = b * Sn + qt * 64 + w * 16;
    const f16x8 qa = *(const f16x8*)(q_ws + (size_t)(qrow0 + n) * DKn + quad * 8);

    // Fragment LDS offsets (f16 units), lane constants.
    int koff[4];   // chunk = g*64 + n*4 + (quad ^ ((n>>1)&3))
#pragma unroll
    for (int g = 0; g < 4; ++g)
        koff[g] = (g * 64 + n * 4 + (quad ^ ((n >> 1) & 3))) * 8;
    int voff[2][2];  // chunk = (h*16+n)*8 + ((ks*4+quad) ^ (n&7))
#pragma unroll
    for (int ks = 0; ks < 2; ++ks) {
        voff[0][ks] = (n * 8 + ((ks * 4 + quad) ^ (n & 7))) * 8;
        voff[1][ks] = ((16 + n) * 8 + ((ks * 4 + quad) ^ (n & 7))) * 8;
    }

    // P LDS addressing (R3-verified conflict-free).
    f16* pw = psh + w * 16 * 64;
    const f16* prd0 = pw + n * 64 + ((quad ^ (n & 7)) << 3);
    const f16* prd1 = pw + n * 64 + (((4 + quad) ^ (n & 7)) << 3);
    int pwo[16];
#pragma unroll
    for (int r = 0; r < 4; ++r) {
        const int row = quad * 4 + r;
#pragma unroll
        for (int g = 0; g < 4; ++g)
            pwo[r * 4 + g] =
                row * 64 + (((g * 2 + (n >> 3)) ^ (row & 7)) << 3) + (n & 7);
    }

    f32x4 o0 = {0.f, 0.f, 0.f, 0.f};
    f32x4 o1 = {0.f, 0.f, 0.f, 0.f};
    float l[4] = {0.f, 0.f, 0.f, 0.f};
    const f32x4 zero = {0.f, 0.f, 0.f, 0.f};

    STAGE(0, 0)
    STAGE(1, 1)

#pragma unroll 1
    for (int kt = 0; kt < Sn / 64; ++kt) {
        const int cur = kt % 3;
        WAIT_VM2;                          // this wave's tile-kt DMAs done
        __builtin_amdgcn_s_barrier();      // all 4 waves' quarters visible
        STAGE((kt + 2) & 31, (kt + 2) % 3) // prefetch distance 2

        const f16* Kt = &kv[cur][0][0];
        const f16* Vt = &kv[cur][1][0];

        const f16x8 kb0 = *(const f16x8*)(Kt + koff[0]);
        const f16x8 kb1 = *(const f16x8*)(Kt + koff[1]);
        const f16x8 kb2 = *(const f16x8*)(Kt + koff[2]);
        const f16x8 kb3 = *(const f16x8*)(Kt + koff[3]);
        const f16x8 va0 = *(const f16x8*)(Vt + voff[0][0]);
        const f16x8 va1 = *(const f16x8*)(Vt + voff[0][1]);
        const f16x8 va2 = *(const f16x8*)(Vt + voff[1][0]);
        const f16x8 va3 = *(const f16x8*)(Vt + voff[1][1]);

        const f32x4 s0 = __builtin_amdgcn_mfma_f32_16x16x32_f16(qa, kb0, zero, 0, 0, 0);
        const f32x4 s1 = __builtin_amdgcn_mfma_f32_16x16x32_f16(qa, kb1, zero, 0, 0, 0);
        const f32x4 s2 = __builtin_amdgcn_mfma_f32_16x16x32_f16(qa, kb2, zero, 0, 0, 0);
        const f32x4 s3 = __builtin_amdgcn_mfma_f32_16x16x32_f16(qa, kb3, zero, 0, 0, 0);

#pragma unroll
        for (int r = 0; r < 4; ++r) {
            const float p0 = __builtin_amdgcn_exp2f(s0[r]);
            const float p1 = __builtin_amdgcn_exp2f(s1[r]);
            const float p2 = __builtin_amdgcn_exp2f(s2[r]);
            const float p3 = __builtin_amdgcn_exp2f(s3[r]);
            l[r] += (p0 + p1) + (p2 + p3);
            pw[pwo[r * 4 + 0]] = (f16)p0;
            pw[pwo[r * 4 + 1]] = (f16)p1;
            pw[pwo[r * 4 + 2]] = (f16)p2;
            pw[pwo[r * 4 + 3]] = (f16)p3;
        }

        const f16x8 pa0 = *(const f16x8*)prd0;
        const f16x8 pa1 = *(const f16x8*)prd1;
        o0 = __builtin_amdgcn_mfma_f32_16x16x32_f16(pa0, va0, o0, 0, 0, 0);
        o0 = __builtin_amdgcn_mfma_f32_16x16x32_f16(pa1, va1, o0, 0, 0, 0);
        o1 = __builtin_amdgcn_mfma_f32_16x16x32_f16(pa0, va2, o1, 0, 0, 0);
        o1 = __builtin_amdgcn_mfma_f32_16x16x32_f16(pa1, va3, o1, 0, 0, 0);
    }
#undef STAGE
    WAIT_VM0;   // drain tail prefetches before LDS reuse/exit

    // l reduction across the 16-lane group
#pragma unroll
    for (int r = 0; r < 4; ++r) {
        float v = l[r];
        v += __shfl_xor(v, 1, 16);
        v += __shfl_xor(v, 2, 16);
        v += __shfl_xor(v, 4, 16);
        v += __shfl_xor(v, 8, 16);
        l[r] = v;
    }

    // epilogue: out[row][f] = sum_d (O[row][d]/l) * Wo_eff[d][f] + bo[f]
    float w0f[FILTn], w1f[FILTn];
#pragma unroll
    for (int f = 0; f < FILTn; ++f) {
        w0f[f] = misc[MISC_WOEFF + n * FILTn + f];
        w1f[f] = misc[MISC_WOEFF + (16 + n) * FILTn + f];
    }
#pragma unroll
    for (int r = 0; r < 4; ++r) {
        const float inv = 1.f / l[r];
        const float a0 = o0[r] * inv;
        const float a1 = o1[r] * inv;
#pragma unroll
        for (int f = 0; f < FILTn; ++f) {
            float v = a0 * w0f[f] + a1 * w1f[f];
            v += __shfl_xor(v, 1, 16);
            v += __shfl_xor(v, 2, 16);
            v += __shfl_xor(v, 4, 16);
            v += __shfl_xor(v, 8, 16);
            if (n == f) {
                const int row = qrow0 + quad * 4 + r;
                out[(size_t)row * FILTn + f] = v + misc[MISC_BO + f];
            }
        }
    }
}

// ---------------------------------------------------------------------------
// Launch. ws layout (f16): q_ws | k_ws | v_ws (4 MiB each), wtg, misc.
// ---------------------------------------------------------------------------
extern "C" void kernel_launch(void* const* d_in, const int* in_sizes, int n_in,
                              void* d_out, int out_size, void* d_ws,
                              size_t ws_size, hipStream_t stream)
{
    const float* q_in = (const float*)d_in[0];
    const float* k_in = (const float*)d_in[1];
    const float* v_in = (const float*)d_in[2];
    const float* Wq   = (const float*)d_in[3];
    const float* bq   = (const float*)d_in[4];
    const float* Wk   = (const float*)d_in[5];
    const float* bk   = (const float*)d_in[6];
    const float* Wv   = (const float*)d_in[7];
    const float* bv   = (const float*)d_in[8];
    const float* Wo   = (const float*)d_in[9];
    const float* bo   = (const float*)d_in[10];
    float* out = (float*)d_out;

    f16*   ws   = (f16*)d_ws;
    f16*   q_ws = ws;
    f16*   k_ws = ws + (size_t)Mn * DKn;
    f16*   v_ws = ws + 2 * (size_t)Mn * DKn;
    f16*   wtg  = ws + 3 * (size_t)Mn * DKn;
    float* misc = (float*)(wtg + 3 * 4096);

    prep_kernel<<<16, 256, 0, stream>>>(Wq, bq, Wk, bk, Wv, bv, Wo, bo, wtg, misc);

    qkv_proj<<<3 * 512, 256, 0, stream>>>(
        q_in, k_in, v_in, wtg, misc, q_ws, k_ws, v_ws);

    flash_mfma<<<Bn * (Sn / 64), 256, 0, stream>>>(
        q_ws, k_ws, v_ws, misc, out);
}

// Round 8
// 174.326 us; speedup vs baseline: 1.3302x; 1.0657x over previous
//
#include <hip/hip_runtime.h>
#include <stdint.h>

using f16 = _Float16;
typedef _Float16 f16x8 __attribute__((ext_vector_type(8)));
typedef _Float16 f16x4 __attribute__((ext_vector_type(4)));
typedef float f32x4 __attribute__((ext_vector_type(4)));

constexpr int Bn    = 32;
constexpr int Sn    = 2048;
constexpr int Fn    = 128;
constexpr int DKn   = 32;
constexpr int NHn   = 16;
constexpr int FILTn = 3;
constexpr int Mn    = Bn * Sn;

// softmax scale (1/sqrt(32)) * log2(e), folded into Wq/bq at prep time.
constexpr float QSCALE = 0.1767766952966369f * 1.4426950408889634f;

// misc layout (float)
constexpr int MISC_WOEFF = 0;
constexpr int MISC_BO    = 96;
constexpr int MISC_BQ    = 99;
constexpr int MISC_BK    = 131;
constexpr int MISC_BV    = 163;

// Async global->LDS 16B copy. LDS dest = wave-uniform base + lane*16 (m104).
#define ASYNC_COPY16(gp, lp)                                                   \
    __builtin_amdgcn_global_load_lds(                                          \
        (const __attribute__((address_space(1))) uint32_t*)(const void*)(gp),  \
        (__attribute__((address_space(3))) uint32_t*)(lp), 16, 0, 0)

// s_waitcnt imm: [3:0] vmcnt, [6:4] expcnt, [11:8] lgkmcnt
#define WAIT_VM2 __builtin_amdgcn_s_waitcnt(0xF72)  // vmcnt<=2
#define WAIT_VM0 __builtin_amdgcn_s_waitcnt(0xF70)  // vmcnt<=0

// ---------------------------------------------------------------------------
// Prep kernel: pack W^T into MFMA B-fragment order (f16, scaled) + misc.
// ---------------------------------------------------------------------------
__global__ __launch_bounds__(256) void prep_kernel(
    const float* __restrict__ Wq, const float* __restrict__ bq,
    const float* __restrict__ Wk, const float* __restrict__ bk,
    const float* __restrict__ Wv, const float* __restrict__ bv,
    const float* __restrict__ Wo, const float* __restrict__ bo,
    f16* __restrict__ wtg, float* __restrict__ misc)
{
    for (int idx = blockIdx.x * 256 + threadIdx.x; idx < 3 * 4096;
         idx += gridDim.x * 256) {
        const int T    = idx >> 12;
        const int r    = idx & 4095;
        const int nt   = r >> 11;
        const int ks   = (r >> 9) & 3;
        const int lane = (r >> 3) & 63;
        const int j    = r & 7;
        const int k    = ks * 32 + (lane >> 4) * 8 + j;
        const int c    = nt * 16 + (lane & 15);
        const float* W = (T == 0) ? Wq : ((T == 1) ? Wk : Wv);
        const float sc = (T == 0) ? QSCALE : 1.0f;
        wtg[idx] = (f16)(W[k * DKn + c] * sc);
    }
    if (blockIdx.x == 0) {
        const int t = threadIdx.x;
        if (t < 96) {
            const int d = t / 3, f = t - 3 * d;
            float s = 0.f;
#pragma unroll
            for (int h = 0; h < NHn; ++h) s += Wo[(h * DKn + d) * FILTn + f];
            misc[MISC_WOEFF + t] = s;
        } else if (t < 99) {
            misc[MISC_BO + (t - 96)] = bo[t - 96];
        } else if (t < 131) {
            misc[MISC_BQ + (t - 99)] = bq[t - 99] * QSCALE;
        } else if (t < 163) {
            misc[MISC_BK + (t - 131)] = bk[t - 131];
        } else if (t < 195) {
            misc[MISC_BV + (t - 163)] = bv[t - 163];
        }
    }
}

// ---------------------------------------------------------------------------
// Kernel A: QKV projection (unchanged from R6 — evidence says proj is not the
// bottleneck). 2 row-groups per wave for MLP; V computed transposed.
// ---------------------------------------------------------------------------
__global__ __launch_bounds__(256) void qkv_proj(
    const float* __restrict__ q_in, const float* __restrict__ k_in,
    const float* __restrict__ v_in,
    const f16* __restrict__ wtg, const float* __restrict__ misc,
    f16* __restrict__ q_ws, f16* __restrict__ k_ws, f16* __restrict__ v_ws)
{
    const int t    = threadIdx.x;
    const int w    = t >> 6;
    const int lane = t & 63;
    const int n    = lane & 15;
    const int quad = lane >> 4;
    const int T    = blockIdx.x / 512;
    const int rowA = (((blockIdx.x - T * 512) * 4 + w)) * 32;
    const int rowB = rowA + 16;
    const float* in = (T == 0) ? q_in : ((T == 1) ? k_in : v_in);

    f16x8 wf[2][4];
#pragma unroll
    for (int nt = 0; nt < 2; ++nt)
#pragma unroll
        for (int ks = 0; ks < 4; ++ks)
            wf[nt][ks] =
                *(const f16x8*)(wtg + T * 4096 + (nt * 4 + ks) * 512 + lane * 8);

    f16x8 afA[4], afB[4];
#pragma unroll
    for (int ks = 0; ks < 4; ++ks) {
        const float* pA = in + (size_t)(rowA + n) * Fn + ks * 32 + quad * 8;
        const float* pB = in + (size_t)(rowB + n) * Fn + ks * 32 + quad * 8;
        const float4 a0 = *(const float4*)pA;
        const float4 a1 = *(const float4*)(pA + 4);
        const float4 b0 = *(const float4*)pB;
        const float4 b1 = *(const float4*)(pB + 4);
        f16x8 a, b;
        a[0]=(f16)a0.x; a[1]=(f16)a0.y; a[2]=(f16)a0.z; a[3]=(f16)a0.w;
        a[4]=(f16)a1.x; a[5]=(f16)a1.y; a[6]=(f16)a1.z; a[7]=(f16)a1.w;
        b[0]=(f16)b0.x; b[1]=(f16)b0.y; b[2]=(f16)b0.z; b[3]=(f16)b0.w;
        b[4]=(f16)b1.x; b[5]=(f16)b1.y; b[6]=(f16)b1.z; b[7]=(f16)b1.w;
        afA[ks] = a;
        afB[ks] = b;
    }

    if (T < 2) {
        const float* bb = misc + (T == 0 ? MISC_BQ : MISC_BK);
        const float b0 = bb[n], b1 = bb[16 + n];
        f32x4 accA0 = {b0, b0, b0, b0}, accA1 = {b1, b1, b1, b1};
        f32x4 accB0 = {b0, b0, b0, b0}, accB1 = {b1, b1, b1, b1};
#pragma unroll
        for (int ks = 0; ks < 4; ++ks) {
            accA0 = __builtin_amdgcn_mfma_f32_16x16x32_f16(afA[ks], wf[0][ks], accA0, 0, 0, 0);
            accA1 = __builtin_amdgcn_mfma_f32_16x16x32_f16(afA[ks], wf[1][ks], accA1, 0, 0, 0);
            accB0 = __builtin_amdgcn_mfma_f32_16x16x32_f16(afB[ks], wf[0][ks], accB0, 0, 0, 0);
            accB1 = __builtin_amdgcn_mfma_f32_16x16x32_f16(afB[ks], wf[1][ks], accB1, 0, 0, 0);
        }
        f16* ows = (T == 0) ? q_ws : k_ws;
#pragma unroll
        for (int r = 0; r < 4; ++r) {
            const int ra = rowA + quad * 4 + r;
            const int rb = rowB + quad * 4 + r;
            ows[(size_t)ra * DKn + n]      = (f16)accA0[r];
            ows[(size_t)ra * DKn + 16 + n] = (f16)accA1[r];
            ows[(size_t)rb * DKn + n]      = (f16)accB0[r];
            ows[(size_t)rb * DKn + 16 + n] = (f16)accB1[r];
        }
    } else {
        f32x4 accA0 = {0.f,0.f,0.f,0.f}, accA1 = {0.f,0.f,0.f,0.f};
        f32x4 accB0 = {0.f,0.f,0.f,0.f}, accB1 = {0.f,0.f,0.f,0.f};
#pragma unroll
        for (int ks = 0; ks < 4; ++ks) {
            accA0 = __builtin_amdgcn_mfma_f32_16x16x32_f16(wf[0][ks], afA[ks], accA0, 0, 0, 0);
            accA1 = __builtin_amdgcn_mfma_f32_16x16x32_f16(wf[1][ks], afA[ks], accA1, 0, 0, 0);
            accB0 = __builtin_amdgcn_mfma_f32_16x16x32_f16(wf[0][ks], afB[ks], accB0, 0, 0, 0);
            accB1 = __builtin_amdgcn_mfma_f32_16x16x32_f16(wf[1][ks], afB[ks], accB1, 0, 0, 0);
        }
        const int b  = rowA >> 11;
        const int sA = (rowA & (Sn - 1)) + n;
        const int sB = sA + 16;
#pragma unroll
        for (int r = 0; r < 4; ++r) {
            const int d0 = quad * 4 + r;
            v_ws[((size_t)(b * DKn + d0)) * Sn + sA] =
                (f16)(accA0[r] + misc[MISC_BV + d0]);
            v_ws[((size_t)(b * DKn + 16 + d0)) * Sn + sA] =
                (f16)(accA1[r] + misc[MISC_BV + 16 + d0]);
            v_ws[((size_t)(b * DKn + d0)) * Sn + sB] =
                (f16)(accB0[r] + misc[MISC_BV + d0]);
            v_ws[((size_t)(b * DKn + 16 + d0)) * Sn + sB] =
                (f16)(accB1[r] + misc[MISC_BV + 16 + d0]);
        }
    }
}

// ---------------------------------------------------------------------------
// Kernel B: flash attention + fused output projection — transpose-free PV.
//
// QK^T computed as S^T = MFMA(A=K-frag, B=Q-frag) (fragment layouts for A and
// B are element-identical here). C-layout of S^T puts P[q=n][key=g*16+quad*4+r]
// in lane (n,quad) — exactly the A-fragment of mfma_f32_16x16x16f16
// (A[m=n][k=quad*4+j]). So PV = 8 x K=16 MFMAs with P packed directly from
// registers: no LDS round-trip, no lgkmcnt(0) drain, no psh.
// V fragments: ds_read_b64 from the same swizzled V image (chunk c=d*8+
// (jc^(d&7))), banks octet-distinct. l is a per-lane scalar (q=n).
// ---------------------------------------------------------------------------
__global__ __launch_bounds__(256, 4) void flash_mfma(
    const f16* __restrict__ q_ws, const f16* __restrict__ k_ws,
    const f16* __restrict__ v_ws,
    const float* __restrict__ misc, float* __restrict__ out)
{
    __shared__ f16 kv[3][2][2048];     // [buf][K/V][4 KB tile] = 24 KB

    const int t    = threadIdx.x;
    const int w    = t >> 6;
    const int lane = t & 63;
    const int n    = lane & 15;
    const int quad = lane >> 4;
    const int b    = (blockIdx.x & 7) * 4 + (blockIdx.x >> 8);
    const int qt   = (blockIdx.x >> 3) & 31;

    // Swizzled per-lane DMA source offsets (f16 units, tile-relative). R6.
    const f16* Ksrc = k_ws + (size_t)b * Sn * DKn
                    + (size_t)(t >> 2) * DKn + (((t & 3) ^ ((t >> 3) & 3)) * 8);
    const f16* Vsrc = v_ws + (size_t)b * DKn * Sn
                    + (size_t)(t >> 3) * Sn + (((t & 7) ^ ((t >> 3) & 7)) * 8);

#define STAGE(KT, BUF)                                              \
    {                                                               \
        ASYNC_COPY16(Ksrc + (size_t)(KT) * 2048, &kv[BUF][0][w * 512]); \
        ASYNC_COPY16(Vsrc + (size_t)(KT) * 64,   &kv[BUF][1][w * 512]); \
    }

    const int qrow0 = b * Sn + qt * 64 + w * 16;
    const f16x8 qa = *(const f16x8*)(q_ws + (size_t)(qrow0 + n) * DKn + quad * 8);

    // K fragment offsets (R6, measured 0 conflicts).
    int koff[4];
#pragma unroll
    for (int g = 0; g < 4; ++g)
        koff[g] = (g * 64 + n * 4 + (quad ^ ((n >> 1) & 3))) * 8;

    // V b64 fragment offsets: element V^T[d][key], d=h*16+n,
    // key = s*16 + quad*4 + j. Image chunk (d,jc=key>>3) at pos d*8+(jc^(d&7)).
    int voff2[2][4];
#pragma unroll
    for (int h = 0; h < 2; ++h)
#pragma unroll
        for (int s = 0; s < 4; ++s) {
            const int d  = h * 16 + n;
            const int jc = s * 2 + (quad >> 1);
            voff2[h][s] = (d * 8 + (jc ^ (d & 7))) * 8 + (quad & 1) * 4;
        }

    f32x4 o0 = {0.f, 0.f, 0.f, 0.f};
    f32x4 o1 = {0.f, 0.f, 0.f, 0.f};
    float lsum = 0.f;
    const f32x4 zero = {0.f, 0.f, 0.f, 0.f};

    STAGE(0, 0)
    STAGE(1, 1)

#pragma unroll 1
    for (int kt = 0; kt < Sn / 64; ++kt) {
        const int cur = kt % 3;
        WAIT_VM2;                          // this wave's tile-kt DMAs done
        __builtin_amdgcn_s_barrier();      // all 4 waves' quarters visible
        STAGE((kt + 2) & 31, (kt + 2) % 3) // prefetch distance 2

        const f16* Kt = &kv[cur][0][0];
        const f16* Vt = &kv[cur][1][0];

        const f16x8 kb0 = *(const f16x8*)(Kt + koff[0]);
        const f16x8 kb1 = *(const f16x8*)(Kt + koff[1]);
        const f16x8 kb2 = *(const f16x8*)(Kt + koff[2]);
        const f16x8 kb3 = *(const f16x8*)(Kt + koff[3]);
        f16x4 vb[2][4];
#pragma unroll
        for (int h = 0; h < 2; ++h)
#pragma unroll
            for (int s = 0; s < 4; ++s)
                vb[h][s] = *(const f16x4*)(Vt + voff2[h][s]);

        // S^T: lane(n,quad) reg r = S[q=n][key = g*16 + quad*4 + r]
        const f32x4 s0 = __builtin_amdgcn_mfma_f32_16x16x32_f16(kb0, qa, zero, 0, 0, 0);
        const f32x4 s1 = __builtin_amdgcn_mfma_f32_16x16x32_f16(kb1, qa, zero, 0, 0, 0);
        const f32x4 s2 = __builtin_amdgcn_mfma_f32_16x16x32_f16(kb2, qa, zero, 0, 0, 0);
        const f32x4 s3 = __builtin_amdgcn_mfma_f32_16x16x32_f16(kb3, qa, zero, 0, 0, 0);

        // no-max softmax (scores O(1) for this model, exp2 domain)
        f16x4 pa[4];
#pragma unroll
        for (int g = 0; g < 4; ++g) {
            const f32x4 sg = (g == 0) ? s0 : ((g == 1) ? s1 : ((g == 2) ? s2 : s3));
            const float p0 = __builtin_amdgcn_exp2f(sg[0]);
            const float p1 = __builtin_amdgcn_exp2f(sg[1]);
            const float p2 = __builtin_amdgcn_exp2f(sg[2]);
            const float p3 = __builtin_amdgcn_exp2f(sg[3]);
            lsum += (p0 + p1) + (p2 + p3);
            f16x4 pp;
            pp[0] = (f16)p0; pp[1] = (f16)p1; pp[2] = (f16)p2; pp[3] = (f16)p3;
            pa[g] = pp;
        }

        // PV: A = P (direct from registers), B = V^T frags. K=16 per step.
#pragma unroll
        for (int s = 0; s < 4; ++s) {
            o0 = __builtin_amdgcn_mfma_f32_16x16x16f16(pa[s], vb[0][s], o0, 0, 0, 0);
            o1 = __builtin_amdgcn_mfma_f32_16x16x16f16(pa[s], vb[1][s], o1, 0, 0, 0);
        }
    }
#undef STAGE
    WAIT_VM0;   // drain tail prefetches before exit

    // l: per-lane partial covers q=n, keys {g*16+quad*4+r}; sum across quads.
    float lf = lsum;
    lf += __shfl_xor(lf, 16);
    lf += __shfl_xor(lf, 32);   // now every lane holds l[q = n]

    // epilogue: out[row][f] = sum_d (O[row][d]/l) * Wo_eff[d][f] + bo[f]
    float w0f[FILTn], w1f[FILTn];
#pragma unroll
    for (int f = 0; f < FILTn; ++f) {
        w0f[f] = misc[MISC_WOEFF + n * FILTn + f];
        w1f[f] = misc[MISC_WOEFF + (16 + n) * FILTn + f];
    }
#pragma unroll
    for (int r = 0; r < 4; ++r) {
        const float inv = 1.f / __shfl(lf, quad * 4 + r);  // l for row q=quad*4+r
        const float a0 = o0[r] * inv;
        const float a1 = o1[r] * inv;
#pragma unroll
        for (int f = 0; f < FILTn; ++f) {
            float v = a0 * w0f[f] + a1 * w1f[f];
            v += __shfl_xor(v, 1, 16);
            v += __shfl_xor(v, 2, 16);
            v += __shfl_xor(v, 4, 16);
            v += __shfl_xor(v, 8, 16);
            if (n == f) {
                const int row = qrow0 + quad * 4 + r;
                out[(size_t)row * FILTn + f] = v + misc[MISC_BO + f];
            }
        }
    }
}

// ---------------------------------------------------------------------------
// Launch. ws layout (f16): q_ws | k_ws | v_ws (4 MiB each), wtg, misc.
// ---------------------------------------------------------------------------
extern "C" void kernel_launch(void* const* d_in, const int* in_sizes, int n_in,
                              void* d_out, int out_size, void* d_ws,
                              size_t ws_size, hipStream_t stream)
{
    const float* q_in = (const float*)d_in[0];
    const float* k_in = (const float*)d_in[1];
    const float* v_in = (const float*)d_in[2];
    const float* Wq   = (const float*)d_in[3];
    const float* bq   = (const float*)d_in[4];
    const float* Wk   = (const float*)d_in[5];
    const float* bk   = (const float*)d_in[6];
    const float* Wv   = (const float*)d_in[7];
    const float* bv   = (const float*)d_in[8];
    const float* Wo   = (const float*)d_in[9];
    const float* bo   = (const float*)d_in[10];
    float* out = (float*)d_out;

    f16*   ws   = (f16*)d_ws;
    f16*   q_ws = ws;
    f16*   k_ws = ws + (size_t)Mn * DKn;
    f16*   v_ws = ws + 2 * (size_t)Mn * DKn;
    f16*   wtg  = ws + 3 * (size_t)Mn * DKn;
    float* misc = (float*)(wtg + 3 * 4096);

    prep_kernel<<<16, 256, 0, stream>>>(Wq, bq, Wk, bk, Wv, bv, Wo, bo, wtg, misc);

    qkv_proj<<<3 * 512, 256, 0, stream>>>(
        q_in, k_in, v_in, wtg, misc, q_ws, k_ws, v_ws);

    flash_mfma<<<Bn * (Sn / 64), 256, 0, stream>>>(
        q_ws, k_ws, v_ws, misc, out);
}